// Round 9
// baseline (166.270 us; speedup 1.0000x reference)
//
#include <hip/hip_runtime.h>

#define BATCH  32768
#define ADIM   16
#define HDIM   256
#define DDIM   128
#define KCODES 2048
#define MROWS  64    // batch rows per block (512 threads, 8 waves, 2 blocks/CU)
#define SA     264   // LDS row stride in u16 (256 cols + 8 pad; 528 B, 16B-aligned)

typedef unsigned short u16;
typedef short s16x8 __attribute__((ext_vector_type(8)));   // 8 x bf16 bits (MFMA frag)
typedef u16   u16x4 __attribute__((ext_vector_type(4)));
typedef u16   u16x8 __attribute__((ext_vector_type(8)));
typedef float f32x4 __attribute__((ext_vector_type(4)));

__device__ __forceinline__ float b2f(u16 u) {
    return __uint_as_float(((unsigned)u) << 16);
}
__device__ __forceinline__ u16 f2b(float f) {
    unsigned u = __float_as_uint(f);
    u += 0x7fffu + ((u >> 16) & 1u);   // RNE
    return (u16)(u >> 16);
}
__device__ __forceinline__ s16x8 ldb8(const u16* p) {
    return *reinterpret_cast<const s16x8*>(p);
}
__device__ __forceinline__ s16x8 ldT(const u16* __restrict__ Wp, int T, int lane) {
    return ldb8(Wp + (T << 9) + lane * 8);   // packed tile T, 16B/lane coalesced
}

// Swapped-operand GEMM: acc[i][j] = W-tile(j) x act-tile(i)^T.
// mfma(Wfrag, actfrag): D row (quad*4+r) = feature-in-tile, D col (lane&15) = batch row.
// Per lane: 4 CONSECUTIVE features of one batch row -> packed 8B epilogue stores.
// NI=4 (64 rows): weight fragments reused across 64 batch rows -> MFMA:ldT = 8:2.
// (R2 lesson: NI=2 doubled per-wave global loads -> +17 us latency stall. Keep NI=4.)
template<int NI, int NT, int KC, int PRE>
__device__ __forceinline__ void gemm_pre(const u16* __restrict__ A,
                                         const u16* __restrict__ Wp, int KT, int jn0,
                                         const s16x8* __restrict__ preW,
                                         int lane, int lrow, int kq, f32x4 (&acc)[NI][NT])
{
    #pragma unroll
    for (int kc = 0; kc < KC; ++kc) {
        s16x8 b[NI], a[NT];
        #pragma unroll
        for (int i = 0; i < NI; ++i) b[i] = ldb8(A + (i * 16 + lrow) * SA + kc * 32 + kq);
        #pragma unroll
        for (int j = 0; j < NT; ++j)
            a[j] = (kc < PRE) ? preW[j * PRE + kc] : ldT(Wp, (jn0 + j) * KT + kc, lane);
        #pragma unroll
        for (int i = 0; i < NI; ++i)
            #pragma unroll
            for (int j = 0; j < NT; ++j)
                acc[i][j] = __builtin_amdgcn_mfma_f32_16x16x32_bf16(a[j], b[i], acc[i][j], 0, 0, 0);
    }
}

// R8: bias folded into the MFMA C-input (acc init = bias broadcast, not 0).
// Mathematically identical (linear), saves the epilogue bias-add in every stage.
template<int NI, int NT>
__device__ __forceinline__ void acc_init_bias(const float* __restrict__ bias, int n0,
                                              int quad, f32x4 (&acc)[NI][NT])
{
    #pragma unroll
    for (int j = 0; j < NT; ++j) {
        const f32x4 bv = *reinterpret_cast<const f32x4*>(bias + n0 + j * 16 + quad * 4);
        #pragma unroll
        for (int i = 0; i < NI; ++i) acc[i][j] = bv;
    }
}

// Epilogue (swapped layout): optional relu, packed 4xbf16 (8B) stores.
// row = i*16 + (lane&15), features n0 + j*16 + quad*4 + r (r=0..3 contiguous).
template<int NI, int NT>
__device__ __forceinline__ void epilogue_st(u16* __restrict__ out, int n0,
                                            int lrow, int quad, bool relu, f32x4 (&acc)[NI][NT])
{
    #pragma unroll
    for (int j = 0; j < NT; ++j) {
        #pragma unroll
        for (int i = 0; i < NI; ++i) {
            u16x4 o;
            #pragma unroll
            for (int r = 0; r < 4; ++r) {
                float v = acc[i][j][r];
                if (relu) v = fmaxf(v, 0.f);
                o[r] = f2b(v);
            }
            *reinterpret_cast<u16x4*>(out + (i * 16 + lrow) * SA + n0 + j * 16 + quad * 4) = o;
        }
    }
}

// One S4 chunk: enc fragments from REGISTERS (true hoist, see R8 keep-alive),
// E-tile fragments from the 2-deep software pipeline.
__device__ __forceinline__ void s4_chunk(const s16x8 (&afr)[4][4],
                                         const float* __restrict__ enorms,
                                         const s16x8 (&e)[4], int code0,
                                         int quad,
                                         float (&minv)[4], int (&mini)[4])
{
    f32x4 acc[4];
    #pragma unroll
    for (int i = 0; i < 4; ++i) { f32x4 z = {0.f, 0.f, 0.f, 0.f}; acc[i] = z; }
    #pragma unroll
    for (int kc = 0; kc < 4; ++kc)
        #pragma unroll
        for (int i = 0; i < 4; ++i)
            acc[i] = __builtin_amdgcn_mfma_f32_16x16x32_bf16(e[kc], afr[kc][i], acc[i], 0, 0, 0);
    const f32x4 en = *reinterpret_cast<const f32x4*>(enorms + code0 + quad * 4);
    #pragma unroll
    for (int i = 0; i < 4; ++i)
        #pragma unroll
        for (int r = 0; r < 4; ++r) {
            const float d2 = fmaf(-2.f, acc[i][r], en[r]);
            if (d2 < minv[i]) { minv[i] = d2; mini[i] = code0 + quad * 4 + r; }
        }
}

#define S4_ISSUE(dst, tile)                                              \
    {                                                                    \
        _Pragma("unroll")                                                \
        for (int kc_ = 0; kc_ < 4; ++kc_)                                \
            dst[kc_] = ldT(Ep, (tile) * 4 + kc_, lane);                  \
    }

// ---------------- prep: fragment-pack all weights + E to bf16, E row norms, zero sums.
// packed[(T<<9)+lane*8+t] = W[(j*16+lane%16)*K + kc*32 + (lane/16)*8 + t], T=j*KT+kc.
// Blocks: We2[0,32) We3[32,48) Wd1[48,64) Wd2[64,96) Wh[96,98) We1[98,102) E[102,230)
__global__ __launch_bounds__(256) void vqvae_prep(
    const float* __restrict__ Ef,   const float* __restrict__ We1f,
    const float* __restrict__ We2f, const float* __restrict__ We3f,
    const float* __restrict__ Wd1f, const float* __restrict__ Wd2f,
    const float* __restrict__ Whf,
    u16* __restrict__ Ep,   u16* __restrict__ We1p,
    u16* __restrict__ We2p, u16* __restrict__ We3p,
    u16* __restrict__ Wd1p, u16* __restrict__ Wd2p,
    u16* __restrict__ Whp,  float* __restrict__ ws)
{
    __shared__ float ep[4][16];
    const int b = blockIdx.x, tid = threadIdx.x;
    const int lane = tid & 63, wv = tid >> 6;
    const int lrow = lane & 15, quad = lane >> 4;

    if (b == 0 && tid < 3) {
        if (tid == 2) reinterpret_cast<unsigned*>(ws)[2] = 0u;
        else ws[tid] = 0.f;
    }

    if (b < 98) {
        const float* src; u16* dst; int KT, Tb;
        if      (b < 32) { src = We2f; dst = We2p; KT = 8; Tb = b * 4; }
        else if (b < 48) { src = We3f; dst = We3p; KT = 8; Tb = (b - 32) * 4; }
        else if (b < 64) { src = Wd1f; dst = Wd1p; KT = 4; Tb = (b - 48) * 4; }
        else if (b < 96) { src = Wd2f; dst = Wd2p; KT = 8; Tb = (b - 64) * 4; }
        else             { src = Whf;  dst = Whp;  KT = 8; Tb = (b - 96) * 4; }
        const int T = Tb + wv;
        const int j = T / KT, kc = T % KT;
        const float* p = src + (j * 16 + lrow) * (KT * 32) + kc * 32 + quad * 8;
        const float4 v0 = *reinterpret_cast<const float4*>(p);
        const float4 v1 = *reinterpret_cast<const float4*>(p + 4);
        u16x8 o;
        o[0] = f2b(v0.x); o[1] = f2b(v0.y); o[2] = f2b(v0.z); o[3] = f2b(v0.w);
        o[4] = f2b(v1.x); o[5] = f2b(v1.y); o[6] = f2b(v1.z); o[7] = f2b(v1.w);
        *reinterpret_cast<u16x8*>(dst + (T << 9) + lane * 8) = o;
    } else if (b < 102) {
        // We1 (256x16), K zero-padded to 32: KT=1, tile=j.
        const int T = (b - 98) * 4 + wv;
        u16x8 o = {0, 0, 0, 0, 0, 0, 0, 0};
        if (quad < 2) {
            const float* p = We1f + (T * 16 + lrow) * ADIM + quad * 8;
            const float4 v0 = *reinterpret_cast<const float4*>(p);
            const float4 v1 = *reinterpret_cast<const float4*>(p + 4);
            o[0] = f2b(v0.x); o[1] = f2b(v0.y); o[2] = f2b(v0.z); o[3] = f2b(v0.w);
            o[4] = f2b(v1.x); o[5] = f2b(v1.y); o[6] = f2b(v1.z); o[7] = f2b(v1.w);
        }
        *reinterpret_cast<u16x8*>(We1p + (T << 9) + lane * 8) = o;
    } else {
        // E (2048x128): KT=4; block covers one 16-code group jb, kc = wv. Also |e|^2.
        const int jb = b - 102;
        const int T = jb * 4 + wv;
        const float* p = Ef + (jb * 16 + lrow) * DDIM + wv * 32 + quad * 8;
        const float4 v0 = *reinterpret_cast<const float4*>(p);
        const float4 v1 = *reinterpret_cast<const float4*>(p + 4);
        u16x8 o;
        o[0] = f2b(v0.x); o[1] = f2b(v0.y); o[2] = f2b(v0.z); o[3] = f2b(v0.w);
        o[4] = f2b(v1.x); o[5] = f2b(v1.y); o[6] = f2b(v1.z); o[7] = f2b(v1.w);
        *reinterpret_cast<u16x8*>(Ep + (T << 9) + lane * 8) = o;
        float s = 0.f;
        #pragma unroll
        for (int t = 0; t < 8; ++t) { const float f = b2f(o[t]); s += f * f; }
        s += __shfl_xor(s, 16, 64);
        s += __shfl_xor(s, 32, 64);
        if (lane < 16) ep[wv][lane] = s;
        __syncthreads();
        if (tid < 16) ws[4 + jb * 16 + tid] = ep[0][tid] + ep[1][tid] + ep[2][tid] + ep[3][tid];
    }
}

// ---------------- main fused kernel: 64 rows/block, 8 waves, 2 blocks/CU (16 waves/CU),
// swapped-operand MFMA, ping-pong LDS, packed W/E, cross-barrier prefetch.
// R7 post-mortem: VGPR=76 and LDS-conflict counter identical across R5-R7 -> the
// compiler kept a 6-waves/EU register target and REMATERIALIZED the S4 afr LDS reads
// (256 redundant ds_read_b128/wave). Occupancy is LDS-capped at 4 waves/EU anyway, so:
//  - amdgpu_waves_per_eu(4,4): tell the allocator the real occupancy -> 128-reg budget
//  - asm keep-alive on afr: forbid remat -> true one-time hoist (16 reads/wave)
//  - bias folded into acc init; S4's first E-issues hoisted before the S3 barrier.
// Tripwire: WRITE_SIZE must stay ~48 KB (spill), VGPR_Count should read 110-128.
__global__ __launch_bounds__(512) __attribute__((amdgpu_waves_per_eu(4, 4)))
void ActionVQVAE_49452253446164_kernel(
    const float* __restrict__ action,
    const u16* __restrict__ We1p, const float* __restrict__ be1,
    const u16* __restrict__ We2p, const float* __restrict__ be2,
    const u16* __restrict__ We3p, const float* __restrict__ be3,
    const u16* __restrict__ Ep,   const float* __restrict__ enorms,
    const u16* __restrict__ Wd1p, const float* __restrict__ bd1,
    const u16* __restrict__ Wd2p, const float* __restrict__ bd2,
    const u16* __restrict__ Whp,  const float* __restrict__ bh,
    float* __restrict__ sums, unsigned* __restrict__ counter, float* __restrict__ out)
{
    __shared__ u16   bufA[MROWS * SA];   // h1 -> enc(cols 0..127) -> d1
    __shared__ u16   bufB[MROWS * SA];   // h2 -> q(cols 0..127) -> d2
    __shared__ float red_val[8][MROWS];
    __shared__ int   red_idx[8][MROWS];
    __shared__ int   qidx[MROWS];
    __shared__ float wsum[16];

    const int tid  = threadIdx.x;
    const int wave = tid >> 6;           // 0..7
    const int lane = tid & 63;
    const int lrow = lane & 15;
    const int quad = lane >> 4;
    const int kq   = quad * 8;
    const int base = blockIdx.x * MROWS;

    float vq_acc = 0.f, rec_acc = 0.f;
    s16x8 preW[8];   // cross-barrier weight-fragment prefetch staging

    // ---------- S1: h1 = relu(action @ We1^T + be1) -> A   (K=16 zero-padded; NT=2)
    {
        s16x8 w1[2];
        #pragma unroll
        for (int j = 0; j < 2; ++j) w1[j] = ldT(We1p, wave * 2 + j, lane);
        f32x4 acc[4][2];
        acc_init_bias<4, 2>(be1, wave * 32, quad, acc);
        s16x8 b[4];
        s16x8 zf = {0, 0, 0, 0, 0, 0, 0, 0};
        #pragma unroll
        for (int i = 0; i < 4; ++i) b[i] = zf;
        if (quad < 2) {
            #pragma unroll
            for (int i = 0; i < 4; ++i) {
                const float* p = action + (base + i * 16 + lrow) * ADIM + kq;
                const float4 v0 = *reinterpret_cast<const float4*>(p);
                const float4 v1 = *reinterpret_cast<const float4*>(p + 4);
                s16x8 f;
                f[0] = (short)f2b(v0.x); f[1] = (short)f2b(v0.y);
                f[2] = (short)f2b(v0.z); f[3] = (short)f2b(v0.w);
                f[4] = (short)f2b(v1.x); f[5] = (short)f2b(v1.y);
                f[6] = (short)f2b(v1.z); f[7] = (short)f2b(v1.w);
                b[i] = f;
            }
        }
        #pragma unroll
        for (int i = 0; i < 4; ++i)
            #pragma unroll
            for (int j = 0; j < 2; ++j)
                acc[i][j] = __builtin_amdgcn_mfma_f32_16x16x32_bf16(w1[j], b[i], acc[i][j], 0, 0, 0);
        // prefetch S2 first 4 kc-slices (j=2 x kc=4) before the barrier
        #pragma unroll
        for (int j = 0; j < 2; ++j)
            #pragma unroll
            for (int kc = 0; kc < 4; ++kc)
                preW[j * 4 + kc] = ldT(We2p, (wave * 2 + j) * 8 + kc, lane);
        epilogue_st<4, 2>(bufA, wave * 32, lrow, quad, true, acc);
    }
    __syncthreads();

    // ---------- S2: h2 = relu(h1 @ We2^T + be2): A -> B   (NT=2, KC=8, PRE=4)
    {
        f32x4 acc[4][2];
        acc_init_bias<4, 2>(be2, wave * 32, quad, acc);
        gemm_pre<4, 2, 8, 4>(bufA, We2p, 8, wave * 2, preW, lane, lrow, kq, acc);
        // prefetch S3 first 4 kc-slices (NT=1)
        #pragma unroll
        for (int kc = 0; kc < 4; ++kc) preW[kc] = ldT(We3p, wave * 8 + kc, lane);
        epilogue_st<4, 2>(bufB, wave * 32, lrow, quad, true, acc);
    }
    __syncthreads();

    // ---------- S3: enc = h2 @ We3^T + be3: B -> A cols 0..127   (NT=1, KC=8, PRE=4)
    s16x8 pA[4], pB[4];                  // S4 E-tile pipeline staging (live across barrier)
    {
        f32x4 acc[4][1];
        acc_init_bias<4, 1>(be3, wave * 16, quad, acc);
        gemm_pre<4, 1, 8, 4>(bufB, We3p, 8, wave, preW, lane, lrow, kq, acc);
        epilogue_st<4, 1>(bufA, wave * 16, lrow, quad, false, acc);
        // issue S4's first two E-tiles BEFORE the barrier: barrier drain covers L2 latency
        S4_ISSUE(pA, wave * 16 + 0);
        S4_ISSUE(pB, wave * 16 + 1);
    }
    __syncthreads();

    // ---------- S4: argmin_k |e_k|^2 - 2*enc.e_k; each wave sweeps 256 codes (16 tiles)
    // enc fragments hoisted once (asm keep-alive forbids remat); E-tiles pipelined 2 ahead.
    {
        float minv[4] = {3.4e38f, 3.4e38f, 3.4e38f, 3.4e38f};
        int   mini[4] = {0, 0, 0, 0};
        const int t0 = wave * 16;

        s16x8 afr[4][4];
        #pragma unroll
        for (int kc = 0; kc < 4; ++kc)
            #pragma unroll
            for (int i = 0; i < 4; ++i) {
                afr[kc][i] = ldb8(bufA + (i * 16 + lrow) * SA + kc * 32 + kq);
                asm volatile("" : "+v"(afr[kc][i]));   // force materialization (no remat)
            }

        // steady state: consume pX(tile), immediately re-issue 2 ahead into pX
        #pragma unroll 1
        for (int t = 0; t <= 6; ++t) {
            s4_chunk(afr, enorms, pA, (t0 + 2 * t) * 16, quad, minv, mini);
            S4_ISSUE(pA, t0 + 2 * t + 2);
            s4_chunk(afr, enorms, pB, (t0 + 2 * t + 1) * 16, quad, minv, mini);
            S4_ISSUE(pB, t0 + 2 * t + 3);
        }
        // tail: chunks 14,15 (no further issues)
        s4_chunk(afr, enorms, pA, (t0 + 14) * 16, quad, minv, mini);
        s4_chunk(afr, enorms, pB, (t0 + 15) * 16, quad, minv, mini);

        // cross-quad reduce (codes differ only across quads): 2 shfl steps x 4 slices
        #pragma unroll
        for (int off = 16; off < 64; off <<= 1) {
            #pragma unroll
            for (int i = 0; i < 4; ++i) {
                const float ov = __shfl_xor(minv[i], off, 64);
                const int   oi = __shfl_xor(mini[i], off, 64);
                if (ov < minv[i] || (ov == minv[i] && oi < mini[i])) { minv[i] = ov; mini[i] = oi; }
            }
        }
        if (lane < 16) {
            #pragma unroll
            for (int i = 0; i < 4; ++i) {
                red_val[wave][i * 16 + lane] = minv[i];
                red_idx[wave][i * 16 + lane] = mini[i];
            }
        }
        // prefetch S6 first 2 kc-slices (j=2 x kc=2) — independent of the reductions
        #pragma unroll
        for (int j = 0; j < 2; ++j)
            #pragma unroll
            for (int kc = 0; kc < 2; ++kc)
                preW[j * 2 + kc] = ldT(Wd1p, (wave * 2 + j) * 4 + kc, lane);
    }
    __syncthreads();
    if (tid < MROWS) {
        float bv = red_val[0][tid]; int bi = red_idx[0][tid];
        #pragma unroll
        for (int w = 1; w < 8; ++w) {
            const float v = red_val[w][tid]; const int ii = red_idx[w][tid];
            if (v < bv || (v == bv && ii < bi)) { bv = v; bi = ii; }
        }
        qidx[tid] = bi;
    }
    __syncthreads();

    // ---------- S5: gather q from packed E -> B cols 0..127; vq += (enc - q)^2
    {
        const int row  = tid >> 3;             // 64 rows, 8 threads/row
        const int t    = tid & 7;
        const int kc   = t >> 1;
        const int half = t & 1;
        const int code = qidx[row];
        const int T    = (code >> 4) * 4 + kc;
        const u16* eb  = Ep + (T << 9) + (code & 15) * 8;
        #pragma unroll
        for (int h = 0; h < 2; ++h) {
            const int qd  = half * 2 + h;
            const u16x8 qv = *reinterpret_cast<const u16x8*>(eb + qd * 128);
            const int col = kc * 32 + qd * 8;
            const u16x8 ev = *reinterpret_cast<const u16x8*>(bufA + row * SA + col);
            *reinterpret_cast<u16x8*>(bufB + row * SA + col) = qv;
            #pragma unroll
            for (int e = 0; e < 8; ++e) {
                const float d = b2f(ev[e]) - b2f(qv[e]);
                vq_acc += d * d;
            }
        }
    }
    __syncthreads();

    // ---------- S6: d1 = relu(q @ Wd1^T + bd1): B -> A   (NT=2, KC=4, PRE=2)
    {
        f32x4 acc[4][2];
        acc_init_bias<4, 2>(bd1, wave * 32, quad, acc);
        gemm_pre<4, 2, 4, 2>(bufB, Wd1p, 4, wave * 2, preW, lane, lrow, kq, acc);
        // prefetch S7 first 4 kc-slices (j=2 x kc=4)
        #pragma unroll
        for (int j = 0; j < 2; ++j)
            #pragma unroll
            for (int kc = 0; kc < 4; ++kc)
                preW[j * 4 + kc] = ldT(Wd2p, (wave * 2 + j) * 8 + kc, lane);
        epilogue_st<4, 2>(bufA, wave * 32, lrow, quad, true, acc);
    }
    __syncthreads();

    // ---------- S7: d2 = relu(d1 @ Wd2^T + bd2): A -> B   (NT=2, KC=8, PRE=4)
    {
        f32x4 acc[4][2];
        acc_init_bias<4, 2>(bd2, wave * 32, quad, acc);
        gemm_pre<4, 2, 8, 4>(bufA, Wd2p, 8, wave * 2, preW, lane, lrow, kq, acc);
        // prefetch S8 Wh fragments (waves 0..3 only)
        if (wave < 4) {
            #pragma unroll
            for (int kc = 0; kc < 8; ++kc) preW[kc] = ldT(Whp, kc, lane);
        }
        epilogue_st<4, 2>(bufB, wave * 32, lrow, quad, true, acc);
    }
    __syncthreads();

    // ---------- S8: recons = tanh(d2 @ Wh^T + bh); rec += (recons - action)^2 (fp32)
    // Swapped: lane holds 4 consecutive out-features (quad*4+r) of row m0+lrow -> float4 loads.
    if (wave < 4) {
        const int m0 = wave * 16;
        f32x4 acc = *reinterpret_cast<const f32x4*>(bh + quad * 4);   // bias-in-C-init
        #pragma unroll
        for (int kc = 0; kc < 8; ++kc) {
            s16x8 b = ldb8(bufB + (m0 + lrow) * SA + kc * 32 + kq);
            acc = __builtin_amdgcn_mfma_f32_16x16x32_bf16(preW[kc], b, acc, 0, 0, 0);
        }
        const f32x4 av4 = *reinterpret_cast<const f32x4*>(action + (base + m0 + lrow) * ADIM + quad * 4);
        #pragma unroll
        for (int r = 0; r < 4; ++r) {
            const float v = tanhf(acc[r]);
            const float d = v - av4[r];
            rec_acc += d * d;
        }
    }

    // ---------- block reduction + atomics + last-block finalize
    #pragma unroll
    for (int off = 1; off < 64; off <<= 1) {
        vq_acc  += __shfl_xor(vq_acc,  off, 64);
        rec_acc += __shfl_xor(rec_acc, off, 64);
    }
    if (lane == 0) { wsum[wave] = rec_acc; wsum[8 + wave] = vq_acc; }
    __syncthreads();
    if (tid == 0) {
        float r = 0.f, v = 0.f;
        #pragma unroll
        for (int w = 0; w < 8; ++w) { r += wsum[w]; v += wsum[8 + w]; }
        atomicAdd(&sums[0], r);
        atomicAdd(&sums[1], v);
        __threadfence();
        const unsigned old = atomicAdd(counter, 1u);
        if (old == gridDim.x - 1) {
            const float s0 = atomicAdd(&sums[0], 0.f);
            const float s1 = atomicAdd(&sums[1], 0.f);
            const float recons_loss = s0 / (float)(BATCH * ADIM);
            const float vq_loss     = 1.25f * (s1 / (float)(BATCH * DDIM));
            out[0] = recons_loss + vq_loss;
        }
    }
}

extern "C" void kernel_launch(void* const* d_in, const int* in_sizes, int n_in,
                              void* d_out, int out_size, void* d_ws, size_t ws_size,
                              hipStream_t stream)
{
    const float* action = (const float*)d_in[0];
    const float* We1f = (const float*)d_in[1];
    const float* be1  = (const float*)d_in[2];
    const float* We2f = (const float*)d_in[3];
    const float* be2  = (const float*)d_in[4];
    const float* We3f = (const float*)d_in[5];
    const float* be3  = (const float*)d_in[6];
    const float* Ef   = (const float*)d_in[7];
    const float* Wd1f = (const float*)d_in[8];
    const float* bd1  = (const float*)d_in[9];
    const float* Wd2f = (const float*)d_in[10];
    const float* bd2  = (const float*)d_in[11];
    const float* Whf  = (const float*)d_in[12];
    const float* bh   = (const float*)d_in[13];

    float* ws = (float*)d_ws;          // [0]rec [1]vq [2]counter [3]pad [4..2052)enorms
    u16* wb = (u16*)(ws + 2052);       // packed bf16 area, 16B-aligned
    u16* Ep   = wb;                    // 262144
    u16* We1p = Ep   + KCODES * DDIM;  // 8192 (K padded to 32)
    u16* We2p = We1p + HDIM * 32;      // 65536
    u16* We3p = We2p + HDIM * HDIM;    // 32768
    u16* Wd1p = We3p + DDIM * HDIM;    // 32768
    u16* Wd2p = Wd1p + HDIM * DDIM;    // 65536
    u16* Whp  = Wd2p + HDIM * HDIM;    // 4096

    vqvae_prep<<<230, 256, 0, stream>>>(Ef, We1f, We2f, We3f, Wd1f, Wd2f, Whf,
                                        Ep, We1p, We2p, We3p, Wd1p, Wd2p, Whp, ws);
    ActionVQVAE_49452253446164_kernel<<<BATCH / MROWS, 512, 0, stream>>>(
        action, We1p, be1, We2p, be2, We3p, be3,
        Ep, ws + 4, Wd1p, bd1, Wd2p, bd2, Whp, bh,
        ws, (unsigned*)(ws + 2), (float*)d_out);
}

// Round 10
// 142.421 us; speedup vs baseline: 1.1675x; 1.1675x over previous
//
#include <hip/hip_runtime.h>

#define BATCH  32768
#define ADIM   16
#define HDIM   256
#define DDIM   128
#define KCODES 2048
#define MROWS  64    // batch rows per block (512 threads, 8 waves, 2 blocks/CU)
#define SA     264   // LDS row stride in u16 (256 cols + 8 pad; 528 B, 16B-aligned)

typedef unsigned short u16;
typedef short s16x8 __attribute__((ext_vector_type(8)));   // 8 x bf16 bits (MFMA frag, 4 VGPRs)
typedef u16   u16x4 __attribute__((ext_vector_type(4)));
typedef u16   u16x8 __attribute__((ext_vector_type(8)));
typedef float f32x4 __attribute__((ext_vector_type(4)));

__device__ __forceinline__ float b2f(u16 u) {
    return __uint_as_float(((unsigned)u) << 16);
}
__device__ __forceinline__ u16 f2b(float f) {
    unsigned u = __float_as_uint(f);
    u += 0x7fffu + ((u >> 16) & 1u);   // RNE
    return (u16)(u >> 16);
}
__device__ __forceinline__ s16x8 ldb8(const u16* p) {
    return *reinterpret_cast<const s16x8*>(p);
}
__device__ __forceinline__ s16x8 ldT(const u16* __restrict__ Wp, int T, int lane) {
    return ldb8(Wp + (T << 9) + lane * 8);   // packed tile T, 16B/lane coalesced
}

// Swapped-operand GEMM: acc[i][j] = W-tile(j) x act-tile(i)^T.
// mfma(Wfrag, actfrag): D row (quad*4+r) = feature-in-tile, D col (lane&15) = batch row.
// Per lane: 4 CONSECUTIVE features of one batch row -> packed 8B epilogue stores.
// NI=4 (64 rows): weight fragments reused across 64 batch rows -> MFMA:ldT = 8:2.
template<int NI, int NT, int KC, int PRE>
__device__ __forceinline__ void gemm_pre(const u16* __restrict__ A,
                                         const u16* __restrict__ Wp, int KT, int jn0,
                                         const s16x8* __restrict__ preW,
                                         int lane, int lrow, int kq, f32x4 (&acc)[NI][NT])
{
    #pragma unroll
    for (int kc = 0; kc < KC; ++kc) {
        s16x8 b[NI], a[NT];
        #pragma unroll
        for (int i = 0; i < NI; ++i) b[i] = ldb8(A + (i * 16 + lrow) * SA + kc * 32 + kq);
        #pragma unroll
        for (int j = 0; j < NT; ++j)
            a[j] = (kc < PRE) ? preW[j * PRE + kc] : ldT(Wp, (jn0 + j) * KT + kc, lane);
        #pragma unroll
        for (int i = 0; i < NI; ++i)
            #pragma unroll
            for (int j = 0; j < NT; ++j)
                acc[i][j] = __builtin_amdgcn_mfma_f32_16x16x32_bf16(a[j], b[i], acc[i][j], 0, 0, 0);
    }
}

// Bias folded into the MFMA C-input (acc init = bias broadcast, not 0).
template<int NI, int NT>
__device__ __forceinline__ void acc_init_bias(const float* __restrict__ bias, int n0,
                                              int quad, f32x4 (&acc)[NI][NT])
{
    #pragma unroll
    for (int j = 0; j < NT; ++j) {
        const f32x4 bv = *reinterpret_cast<const f32x4*>(bias + n0 + j * 16 + quad * 4);
        #pragma unroll
        for (int i = 0; i < NI; ++i) acc[i][j] = bv;
    }
}

// Epilogue (swapped layout): optional relu, packed 4xbf16 (8B) stores.
template<int NI, int NT>
__device__ __forceinline__ void epilogue_st(u16* __restrict__ out, int n0,
                                            int lrow, int quad, bool relu, f32x4 (&acc)[NI][NT])
{
    #pragma unroll
    for (int j = 0; j < NT; ++j) {
        #pragma unroll
        for (int i = 0; i < NI; ++i) {
            u16x4 o;
            #pragma unroll
            for (int r = 0; r < 4; ++r) {
                float v = acc[i][j][r];
                if (relu) v = fmaxf(v, 0.f);
                o[r] = f2b(v);
            }
            *reinterpret_cast<u16x4*>(out + (i * 16 + lrow) * SA + n0 + j * 16 + quad * 4) = o;
        }
    }
}

#define S4_ISSUE(dst, tile)                                              \
    {                                                                    \
        _Pragma("unroll")                                                \
        for (int kc_ = 0; kc_ < 4; ++kc_)                                \
            dst[kc_] = ldT(Ep, (tile) * 4 + kc_, lane);                  \
    }

// One S4 chunk over TWO row-tiles: acc = E-tile x enc(rows rbase..rbase+31).
__device__ __forceinline__ void s4_chunk2(const s16x8 (&afr)[4][2],
                                          const float* __restrict__ enorms,
                                          const s16x8 (&e)[4], int code0,
                                          int quad,
                                          float (&minv)[2], int (&mini)[2])
{
    f32x4 acc[2];
    #pragma unroll
    for (int i = 0; i < 2; ++i) { f32x4 z = {0.f, 0.f, 0.f, 0.f}; acc[i] = z; }
    #pragma unroll
    for (int kc = 0; kc < 4; ++kc)
        #pragma unroll
        for (int i = 0; i < 2; ++i)
            acc[i] = __builtin_amdgcn_mfma_f32_16x16x32_bf16(e[kc], afr[kc][i], acc[i], 0, 0, 0);
    const f32x4 en = *reinterpret_cast<const f32x4*>(enorms + code0 + quad * 4);
    #pragma unroll
    for (int i = 0; i < 2; ++i)
        #pragma unroll
        for (int r = 0; r < 4; ++r) {
            const float d2 = fmaf(-2.f, acc[i][r], en[r]);
            if (d2 < minv[i]) { minv[i] = d2; mini[i] = code0 + quad * 4 + r; }
        }
}

// One S4 pass: 32 batch rows (rbase + i*16 + lrow, i=0,1), all 16 E-tiles of this wave.
// afr hoist = 32 VGPR only -> pass peak ~95 regs, fits the 128 budget (R9 lesson:
// full afr[4][4]=64 hoist + pipeline = ~132 regs = over budget -> remat or spill).
// LDS reads stay 16/wave TOTAL across both passes (8 each). E-tiles re-issued per
// pass (+64 pipelined L2 loads/wave ~ hidden).
__device__ __forceinline__ void s4_pass(const u16* __restrict__ bufA,
                                        const u16* __restrict__ Ep,
                                        const float* __restrict__ enorms,
                                        int t0, int rbase, int lane, int lrow, int quad, int kq,
                                        float (&minv)[2], int (&mini)[2])
{
    s16x8 pA[4], pB[4];
    S4_ISSUE(pA, t0 + 0);
    S4_ISSUE(pB, t0 + 1);
    s16x8 afr[4][2];
    #pragma unroll
    for (int kc = 0; kc < 4; ++kc)
        #pragma unroll
        for (int i = 0; i < 2; ++i) {
            afr[kc][i] = ldb8(bufA + (rbase + i * 16 + lrow) * SA + kc * 32 + kq);
            asm volatile("" : "+v"(afr[kc][i]));   // forbid remat (R7 lesson)
        }
    // steady state: consume pX(tile), immediately re-issue 2 ahead into pX
    #pragma unroll 1
    for (int t = 0; t <= 6; ++t) {
        s4_chunk2(afr, enorms, pA, (t0 + 2 * t) * 16, quad, minv, mini);
        S4_ISSUE(pA, t0 + 2 * t + 2);
        s4_chunk2(afr, enorms, pB, (t0 + 2 * t + 1) * 16, quad, minv, mini);
        S4_ISSUE(pB, t0 + 2 * t + 3);
    }
    s4_chunk2(afr, enorms, pA, (t0 + 14) * 16, quad, minv, mini);
    s4_chunk2(afr, enorms, pB, (t0 + 15) * 16, quad, minv, mini);
}

// ---------------- prep: fragment-pack all weights + E to bf16, E row norms, zero sums.
__global__ __launch_bounds__(256) void vqvae_prep(
    const float* __restrict__ Ef,   const float* __restrict__ We1f,
    const float* __restrict__ We2f, const float* __restrict__ We3f,
    const float* __restrict__ Wd1f, const float* __restrict__ Wd2f,
    const float* __restrict__ Whf,
    u16* __restrict__ Ep,   u16* __restrict__ We1p,
    u16* __restrict__ We2p, u16* __restrict__ We3p,
    u16* __restrict__ Wd1p, u16* __restrict__ Wd2p,
    u16* __restrict__ Whp,  float* __restrict__ ws)
{
    __shared__ float ep[4][16];
    const int b = blockIdx.x, tid = threadIdx.x;
    const int lane = tid & 63, wv = tid >> 6;
    const int lrow = lane & 15, quad = lane >> 4;

    if (b == 0 && tid < 3) {
        if (tid == 2) reinterpret_cast<unsigned*>(ws)[2] = 0u;
        else ws[tid] = 0.f;
    }

    if (b < 98) {
        const float* src; u16* dst; int KT, Tb;
        if      (b < 32) { src = We2f; dst = We2p; KT = 8; Tb = b * 4; }
        else if (b < 48) { src = We3f; dst = We3p; KT = 8; Tb = (b - 32) * 4; }
        else if (b < 64) { src = Wd1f; dst = Wd1p; KT = 4; Tb = (b - 48) * 4; }
        else if (b < 96) { src = Wd2f; dst = Wd2p; KT = 8; Tb = (b - 64) * 4; }
        else             { src = Whf;  dst = Whp;  KT = 8; Tb = (b - 96) * 4; }
        const int T = Tb + wv;
        const int j = T / KT, kc = T % KT;
        const float* p = src + (j * 16 + lrow) * (KT * 32) + kc * 32 + quad * 8;
        const float4 v0 = *reinterpret_cast<const float4*>(p);
        const float4 v1 = *reinterpret_cast<const float4*>(p + 4);
        u16x8 o;
        o[0] = f2b(v0.x); o[1] = f2b(v0.y); o[2] = f2b(v0.z); o[3] = f2b(v0.w);
        o[4] = f2b(v1.x); o[5] = f2b(v1.y); o[6] = f2b(v1.z); o[7] = f2b(v1.w);
        *reinterpret_cast<u16x8*>(dst + (T << 9) + lane * 8) = o;
    } else if (b < 102) {
        // We1 (256x16), K zero-padded to 32: KT=1, tile=j.
        const int T = (b - 98) * 4 + wv;
        u16x8 o = {0, 0, 0, 0, 0, 0, 0, 0};
        if (quad < 2) {
            const float* p = We1f + (T * 16 + lrow) * ADIM + quad * 8;
            const float4 v0 = *reinterpret_cast<const float4*>(p);
            const float4 v1 = *reinterpret_cast<const float4*>(p + 4);
            o[0] = f2b(v0.x); o[1] = f2b(v0.y); o[2] = f2b(v0.z); o[3] = f2b(v0.w);
            o[4] = f2b(v1.x); o[5] = f2b(v1.y); o[6] = f2b(v1.z); o[7] = f2b(v1.w);
        }
        *reinterpret_cast<u16x8*>(We1p + (T << 9) + lane * 8) = o;
    } else {
        // E (2048x128): KT=4; block covers one 16-code group jb, kc = wv. Also |e|^2.
        const int jb = b - 102;
        const int T = jb * 4 + wv;
        const float* p = Ef + (jb * 16 + lrow) * DDIM + wv * 32 + quad * 8;
        const float4 v0 = *reinterpret_cast<const float4*>(p);
        const float4 v1 = *reinterpret_cast<const float4*>(p + 4);
        u16x8 o;
        o[0] = f2b(v0.x); o[1] = f2b(v0.y); o[2] = f2b(v0.z); o[3] = f2b(v0.w);
        o[4] = f2b(v1.x); o[5] = f2b(v1.y); o[6] = f2b(v1.z); o[7] = f2b(v1.w);
        *reinterpret_cast<u16x8*>(Ep + (T << 9) + lane * 8) = o;
        float s = 0.f;
        #pragma unroll
        for (int t = 0; t < 8; ++t) { const float f = b2f(o[t]); s += f * f; }
        s += __shfl_xor(s, 16, 64);
        s += __shfl_xor(s, 32, 64);
        if (lane < 16) ep[wv][lane] = s;
        __syncthreads();
        if (tid < 16) ws[4 + jb * 16 + tid] = ep[0][tid] + ep[1][tid] + ep[2][tid] + ep[3][tid];
    }
}

// ---------------- main fused kernel: 64 rows/block, 8 waves, 2 blocks/CU (16 waves/CU).
// Register-budget model (R1/R4/R9 empirics): budget ~= 256/min_waves_per_eu on this
// toolchain; default min=2 for 512-thd (cap 128), soft target ~76-84. R9's (4,4) set
// budget=64 -> forced-hoist spilled 84 MB. Now: waves_per_eu(2,4) -> budget 128 (the
// LDS-imposed occupancy boundary: 2 blocks x 8 waves needs VGPR <= 128), and S4 is
// TWO-PASS (afr[4][2]=32 regs/pass) so demand ~105 fits with margin.
// Tripwires: VGPR_Count should read 96-128 (64/76 = model wrong); WRITE_SIZE ~48 KB.
__global__ __launch_bounds__(512) __attribute__((amdgpu_waves_per_eu(2, 4)))
void ActionVQVAE_49452253446164_kernel(
    const float* __restrict__ action,
    const u16* __restrict__ We1p, const float* __restrict__ be1,
    const u16* __restrict__ We2p, const float* __restrict__ be2,
    const u16* __restrict__ We3p, const float* __restrict__ be3,
    const u16* __restrict__ Ep,   const float* __restrict__ enorms,
    const u16* __restrict__ Wd1p, const float* __restrict__ bd1,
    const u16* __restrict__ Wd2p, const float* __restrict__ bd2,
    const u16* __restrict__ Whp,  const float* __restrict__ bh,
    float* __restrict__ sums, unsigned* __restrict__ counter, float* __restrict__ out)
{
    __shared__ u16   bufA[MROWS * SA];   // h1 -> enc(cols 0..127) -> d1
    __shared__ u16   bufB[MROWS * SA];   // h2 -> q(cols 0..127) -> d2
    __shared__ float red_val[8][MROWS];
    __shared__ int   red_idx[8][MROWS];
    __shared__ int   qidx[MROWS];
    __shared__ float wsum[16];

    const int tid  = threadIdx.x;
    const int wave = tid >> 6;           // 0..7
    const int lane = tid & 63;
    const int lrow = lane & 15;
    const int quad = lane >> 4;
    const int kq   = quad * 8;
    const int base = blockIdx.x * MROWS;

    float vq_acc = 0.f, rec_acc = 0.f;
    s16x8 preW[8];   // cross-barrier weight-fragment prefetch staging

    // ---------- S1: h1 = relu(action @ We1^T + be1) -> A   (K=16 zero-padded; NT=2)
    {
        s16x8 w1[2];
        #pragma unroll
        for (int j = 0; j < 2; ++j) w1[j] = ldT(We1p, wave * 2 + j, lane);
        f32x4 acc[4][2];
        acc_init_bias<4, 2>(be1, wave * 32, quad, acc);
        s16x8 b[4];
        s16x8 zf = {0, 0, 0, 0, 0, 0, 0, 0};
        #pragma unroll
        for (int i = 0; i < 4; ++i) b[i] = zf;
        if (quad < 2) {
            #pragma unroll
            for (int i = 0; i < 4; ++i) {
                const float* p = action + (base + i * 16 + lrow) * ADIM + kq;
                const float4 v0 = *reinterpret_cast<const float4*>(p);
                const float4 v1 = *reinterpret_cast<const float4*>(p + 4);
                s16x8 f;
                f[0] = (short)f2b(v0.x); f[1] = (short)f2b(v0.y);
                f[2] = (short)f2b(v0.z); f[3] = (short)f2b(v0.w);
                f[4] = (short)f2b(v1.x); f[5] = (short)f2b(v1.y);
                f[6] = (short)f2b(v1.z); f[7] = (short)f2b(v1.w);
                b[i] = f;
            }
        }
        #pragma unroll
        for (int i = 0; i < 4; ++i)
            #pragma unroll
            for (int j = 0; j < 2; ++j)
                acc[i][j] = __builtin_amdgcn_mfma_f32_16x16x32_bf16(w1[j], b[i], acc[i][j], 0, 0, 0);
        // prefetch S2 first 4 kc-slices (j=2 x kc=4) before the barrier
        #pragma unroll
        for (int j = 0; j < 2; ++j)
            #pragma unroll
            for (int kc = 0; kc < 4; ++kc)
                preW[j * 4 + kc] = ldT(We2p, (wave * 2 + j) * 8 + kc, lane);
        epilogue_st<4, 2>(bufA, wave * 32, lrow, quad, true, acc);
    }
    __syncthreads();

    // ---------- S2: h2 = relu(h1 @ We2^T + be2): A -> B   (NT=2, KC=8, PRE=4)
    {
        f32x4 acc[4][2];
        acc_init_bias<4, 2>(be2, wave * 32, quad, acc);
        gemm_pre<4, 2, 8, 4>(bufA, We2p, 8, wave * 2, preW, lane, lrow, kq, acc);
        // prefetch S3 first 4 kc-slices (NT=1)
        #pragma unroll
        for (int kc = 0; kc < 4; ++kc) preW[kc] = ldT(We3p, wave * 8 + kc, lane);
        epilogue_st<4, 2>(bufB, wave * 32, lrow, quad, true, acc);
    }
    __syncthreads();

    // ---------- S3: enc = h2 @ We3^T + be3: B -> A cols 0..127   (NT=1, KC=8, PRE=4)
    {
        f32x4 acc[4][1];
        acc_init_bias<4, 1>(be3, wave * 16, quad, acc);
        gemm_pre<4, 1, 8, 4>(bufB, We3p, 8, wave, preW, lane, lrow, kq, acc);
        epilogue_st<4, 1>(bufA, wave * 16, lrow, quad, false, acc);
    }
    __syncthreads();

    // ---------- S4: argmin_k |e_k|^2 - 2*enc.e_k; each wave sweeps 256 codes (16 tiles)
    // Two passes of 32 rows each; per-pass afr hoist + 2-deep E-tile pipeline.
    {
        const int t0 = wave * 16;
        // pass 0: rows 0..31
        {
            float minv[2] = {3.4e38f, 3.4e38f};
            int   mini[2] = {0, 0};
            s4_pass(bufA, Ep, enorms, t0, 0, lane, lrow, quad, kq, minv, mini);
            #pragma unroll
            for (int off = 16; off < 64; off <<= 1) {
                #pragma unroll
                for (int i = 0; i < 2; ++i) {
                    const float ov = __shfl_xor(minv[i], off, 64);
                    const int   oi = __shfl_xor(mini[i], off, 64);
                    if (ov < minv[i] || (ov == minv[i] && oi < mini[i])) { minv[i] = ov; mini[i] = oi; }
                }
            }
            if (lane < 16) {
                #pragma unroll
                for (int i = 0; i < 2; ++i) {
                    red_val[wave][i * 16 + lane] = minv[i];
                    red_idx[wave][i * 16 + lane] = mini[i];
                }
            }
        }
        // pass 1: rows 32..63
        {
            float minv[2] = {3.4e38f, 3.4e38f};
            int   mini[2] = {0, 0};
            s4_pass(bufA, Ep, enorms, t0, 32, lane, lrow, quad, kq, minv, mini);
            #pragma unroll
            for (int off = 16; off < 64; off <<= 1) {
                #pragma unroll
                for (int i = 0; i < 2; ++i) {
                    const float ov = __shfl_xor(minv[i], off, 64);
                    const int   oi = __shfl_xor(mini[i], off, 64);
                    if (ov < minv[i] || (ov == minv[i] && oi < mini[i])) { minv[i] = ov; mini[i] = oi; }
                }
            }
            if (lane < 16) {
                #pragma unroll
                for (int i = 0; i < 2; ++i) {
                    red_val[wave][32 + i * 16 + lane] = minv[i];
                    red_idx[wave][32 + i * 16 + lane] = mini[i];
                }
            }
        }
        // prefetch S6 first 2 kc-slices (j=2 x kc=2) — independent of the reductions
        #pragma unroll
        for (int j = 0; j < 2; ++j)
            #pragma unroll
            for (int kc = 0; kc < 2; ++kc)
                preW[j * 2 + kc] = ldT(Wd1p, (wave * 2 + j) * 4 + kc, lane);
    }
    __syncthreads();
    if (tid < MROWS) {
        float bv = red_val[0][tid]; int bi = red_idx[0][tid];
        #pragma unroll
        for (int w = 1; w < 8; ++w) {
            const float v = red_val[w][tid]; const int ii = red_idx[w][tid];
            if (v < bv || (v == bv && ii < bi)) { bv = v; bi = ii; }
        }
        qidx[tid] = bi;
    }
    __syncthreads();

    // ---------- S5: gather q from packed E -> B cols 0..127; vq += (enc - q)^2
    {
        const int row  = tid >> 3;             // 64 rows, 8 threads/row
        const int t    = tid & 7;
        const int kc   = t >> 1;
        const int half = t & 1;
        const int code = qidx[row];
        const int T    = (code >> 4) * 4 + kc;
        const u16* eb  = Ep + (T << 9) + (code & 15) * 8;
        #pragma unroll
        for (int h = 0; h < 2; ++h) {
            const int qd  = half * 2 + h;
            const u16x8 qv = *reinterpret_cast<const u16x8*>(eb + qd * 128);
            const int col = kc * 32 + qd * 8;
            const u16x8 ev = *reinterpret_cast<const u16x8*>(bufA + row * SA + col);
            *reinterpret_cast<u16x8*>(bufB + row * SA + col) = qv;
            #pragma unroll
            for (int e = 0; e < 8; ++e) {
                const float d = b2f(ev[e]) - b2f(qv[e]);
                vq_acc += d * d;
            }
        }
    }
    __syncthreads();

    // ---------- S6: d1 = relu(q @ Wd1^T + bd1): B -> A   (NT=2, KC=4, PRE=2)
    {
        f32x4 acc[4][2];
        acc_init_bias<4, 2>(bd1, wave * 32, quad, acc);
        gemm_pre<4, 2, 4, 2>(bufB, Wd1p, 4, wave * 2, preW, lane, lrow, kq, acc);
        // prefetch S7 first 4 kc-slices (j=2 x kc=4)
        #pragma unroll
        for (int j = 0; j < 2; ++j)
            #pragma unroll
            for (int kc = 0; kc < 4; ++kc)
                preW[j * 4 + kc] = ldT(Wd2p, (wave * 2 + j) * 8 + kc, lane);
        epilogue_st<4, 2>(bufA, wave * 32, lrow, quad, true, acc);
    }
    __syncthreads();

    // ---------- S7: d2 = relu(d1 @ Wd2^T + bd2): A -> B   (NT=2, KC=8, PRE=4)
    {
        f32x4 acc[4][2];
        acc_init_bias<4, 2>(bd2, wave * 32, quad, acc);
        gemm_pre<4, 2, 8, 4>(bufA, Wd2p, 8, wave * 2, preW, lane, lrow, kq, acc);
        // prefetch S8 Wh fragments (waves 0..3 only)
        if (wave < 4) {
            #pragma unroll
            for (int kc = 0; kc < 8; ++kc) preW[kc] = ldT(Whp, kc, lane);
        }
        epilogue_st<4, 2>(bufB, wave * 32, lrow, quad, true, acc);
    }
    __syncthreads();

    // ---------- S8: recons = tanh(d2 @ Wh^T + bh); rec += (recons - action)^2 (fp32)
    if (wave < 4) {
        const int m0 = wave * 16;
        f32x4 acc = *reinterpret_cast<const f32x4*>(bh + quad * 4);   // bias-in-C-init
        #pragma unroll
        for (int kc = 0; kc < 8; ++kc) {
            s16x8 b = ldb8(bufB + (m0 + lrow) * SA + kc * 32 + kq);
            acc = __builtin_amdgcn_mfma_f32_16x16x32_bf16(preW[kc], b, acc, 0, 0, 0);
        }
        const f32x4 av4 = *reinterpret_cast<const f32x4*>(action + (base + m0 + lrow) * ADIM + quad * 4);
        #pragma unroll
        for (int r = 0; r < 4; ++r) {
            const float v = tanhf(acc[r]);
            const float d = v - av4[r];
            rec_acc += d * d;
        }
    }

    // ---------- block reduction + atomics + last-block finalize
    #pragma unroll
    for (int off = 1; off < 64; off <<= 1) {
        vq_acc  += __shfl_xor(vq_acc,  off, 64);
        rec_acc += __shfl_xor(rec_acc, off, 64);
    }
    if (lane == 0) { wsum[wave] = rec_acc; wsum[8 + wave] = vq_acc; }
    __syncthreads();
    if (tid == 0) {
        float r = 0.f, v = 0.f;
        #pragma unroll
        for (int w = 0; w < 8; ++w) { r += wsum[w]; v += wsum[8 + w]; }
        atomicAdd(&sums[0], r);
        atomicAdd(&sums[1], v);
        __threadfence();
        const unsigned old = atomicAdd(counter, 1u);
        if (old == gridDim.x - 1) {
            const float s0 = atomicAdd(&sums[0], 0.f);
            const float s1 = atomicAdd(&sums[1], 0.f);
            const float recons_loss = s0 / (float)(BATCH * ADIM);
            const float vq_loss     = 1.25f * (s1 / (float)(BATCH * DDIM));
            out[0] = recons_loss + vq_loss;
        }
    }
}

extern "C" void kernel_launch(void* const* d_in, const int* in_sizes, int n_in,
                              void* d_out, int out_size, void* d_ws, size_t ws_size,
                              hipStream_t stream)
{
    const float* action = (const float*)d_in[0];
    const float* We1f = (const float*)d_in[1];
    const float* be1  = (const float*)d_in[2];
    const float* We2f = (const float*)d_in[3];
    const float* be2  = (const float*)d_in[4];
    const float* We3f = (const float*)d_in[5];
    const float* be3  = (const float*)d_in[6];
    const float* Ef   = (const float*)d_in[7];
    const float* Wd1f = (const float*)d_in[8];
    const float* bd1  = (const float*)d_in[9];
    const float* Wd2f = (const float*)d_in[10];
    const float* bd2  = (const float*)d_in[11];
    const float* Whf  = (const float*)d_in[12];
    const float* bh   = (const float*)d_in[13];

    float* ws = (float*)d_ws;          // [0]rec [1]vq [2]counter [3]pad [4..2052)enorms
    u16* wb = (u16*)(ws + 2052);       // packed bf16 area, 16B-aligned
    u16* Ep   = wb;                    // 262144
    u16* We1p = Ep   + KCODES * DDIM;  // 8192 (K padded to 32)
    u16* We2p = We1p + HDIM * 32;      // 65536
    u16* We3p = We2p + HDIM * HDIM;    // 32768
    u16* Wd1p = We3p + DDIM * HDIM;    // 32768
    u16* Wd2p = Wd1p + HDIM * DDIM;    // 65536
    u16* Whp  = Wd2p + HDIM * HDIM;    // 4096

    vqvae_prep<<<230, 256, 0, stream>>>(Ef, We1f, We2f, We3f, Wd1f, Wd2f, Whf,
                                        Ep, We1p, We2p, We3p, Wd1p, Wd2p, Whp, ws);
    ActionVQVAE_49452253446164_kernel<<<BATCH / MROWS, 512, 0, stream>>>(
        action, We1p, be1, We2p, be2, We3p, be3,
        Ep, ws + 4, Wd1p, bd1, Wd2p, bd2, Whp, bh,
        ws, (unsigned*)(ws + 2), (float*)d_out);
}

// Round 11
// 137.565 us; speedup vs baseline: 1.2087x; 1.0353x over previous
//
#include <hip/hip_runtime.h>

#define BATCH  32768
#define ADIM   16
#define HDIM   256
#define DDIM   128
#define KCODES 2048
#define MROWS  64    // batch rows per block (512 threads, 8 waves, 2 blocks/CU)
#define SA     264   // LDS row stride in u16 (256 cols + 8 pad; 528 B, 16B-aligned)

typedef unsigned short u16;
typedef short s16x8 __attribute__((ext_vector_type(8)));   // 8 x bf16 bits (MFMA frag)
typedef u16   u16x4 __attribute__((ext_vector_type(4)));
typedef u16   u16x8 __attribute__((ext_vector_type(8)));
typedef float f32x4 __attribute__((ext_vector_type(4)));

__device__ __forceinline__ float b2f(u16 u) {
    return __uint_as_float(((unsigned)u) << 16);
}
__device__ __forceinline__ u16 f2b(float f) {
    unsigned u = __float_as_uint(f);
    u += 0x7fffu + ((u >> 16) & 1u);   // RNE
    return (u16)(u >> 16);
}
__device__ __forceinline__ s16x8 ldb8(const u16* p) {
    return *reinterpret_cast<const s16x8*>(p);
}
__device__ __forceinline__ s16x8 ldT(const u16* __restrict__ Wp, int T, int lane) {
    return ldb8(Wp + (T << 9) + lane * 8);   // packed tile T, 16B/lane coalesced
}

// Swapped-operand GEMM: acc[i][j] = W-tile(j) x act-tile(i)^T.
// mfma(Wfrag, actfrag): D row (quad*4+r) = feature-in-tile, D col (lane&15) = batch row.
// NI=4 (64 rows): weight fragments reused across 64 batch rows -> MFMA:ldT = 8:2.
// (R2/R10 lesson: halving rows-per-load-reuse costs ~+6-17 us of latency events.)
template<int NI, int NT, int KC, int PRE>
__device__ __forceinline__ void gemm_pre(const u16* __restrict__ A,
                                         const u16* __restrict__ Wp, int KT, int jn0,
                                         const s16x8* __restrict__ preW,
                                         int lane, int lrow, int kq, f32x4 (&acc)[NI][NT])
{
    #pragma unroll
    for (int kc = 0; kc < KC; ++kc) {
        s16x8 b[NI], a[NT];
        #pragma unroll
        for (int i = 0; i < NI; ++i) b[i] = ldb8(A + (i * 16 + lrow) * SA + kc * 32 + kq);
        #pragma unroll
        for (int j = 0; j < NT; ++j)
            a[j] = (kc < PRE) ? preW[j * PRE + kc] : ldT(Wp, (jn0 + j) * KT + kc, lane);
        #pragma unroll
        for (int i = 0; i < NI; ++i)
            #pragma unroll
            for (int j = 0; j < NT; ++j)
                acc[i][j] = __builtin_amdgcn_mfma_f32_16x16x32_bf16(a[j], b[i], acc[i][j], 0, 0, 0);
    }
}

// Bias folded into the MFMA C-input (acc init = bias broadcast, not 0).
// Mathematically identical (linear); removes epilogue bias-adds (R10: absmax 0.0).
template<int NI, int NT>
__device__ __forceinline__ void acc_init_bias(const float* __restrict__ bias, int n0,
                                              int quad, f32x4 (&acc)[NI][NT])
{
    #pragma unroll
    for (int j = 0; j < NT; ++j) {
        const f32x4 bv = *reinterpret_cast<const f32x4*>(bias + n0 + j * 16 + quad * 4);
        #pragma unroll
        for (int i = 0; i < NI; ++i) acc[i][j] = bv;
    }
}

// Epilogue (swapped layout): optional relu, packed 4xbf16 (8B) stores.
// row = i*16 + (lane&15), features n0 + j*16 + quad*4 + r (r=0..3 contiguous).
template<int NI, int NT>
__device__ __forceinline__ void epilogue_st(u16* __restrict__ out, int n0,
                                            int lrow, int quad, bool relu, f32x4 (&acc)[NI][NT])
{
    #pragma unroll
    for (int j = 0; j < NT; ++j) {
        #pragma unroll
        for (int i = 0; i < NI; ++i) {
            u16x4 o;
            #pragma unroll
            for (int r = 0; r < 4; ++r) {
                float v = acc[i][j][r];
                if (relu) v = fmaxf(v, 0.f);
                o[r] = f2b(v);
            }
            *reinterpret_cast<u16x4*>(out + (i * 16 + lrow) * SA + n0 + j * 16 + quad * 4) = o;
        }
    }
}

// One S4 chunk (R7 champion form): enc fragments afr (compiler-managed — forced
// hoisting/remat games all regressed: R9 spill, R10 two-pass +6us), E-tile from
// the 2-deep software pipeline.
__device__ __forceinline__ void s4_chunk(const s16x8 (&afr)[4][4],
                                         const float* __restrict__ enorms,
                                         const s16x8 (&e)[4], int code0,
                                         int quad,
                                         float (&minv)[4], int (&mini)[4])
{
    f32x4 acc[4];
    #pragma unroll
    for (int i = 0; i < 4; ++i) { f32x4 z = {0.f, 0.f, 0.f, 0.f}; acc[i] = z; }
    #pragma unroll
    for (int kc = 0; kc < 4; ++kc)
        #pragma unroll
        for (int i = 0; i < 4; ++i)
            acc[i] = __builtin_amdgcn_mfma_f32_16x16x32_bf16(e[kc], afr[kc][i], acc[i], 0, 0, 0);
    const f32x4 en = *reinterpret_cast<const f32x4*>(enorms + code0 + quad * 4);
    #pragma unroll
    for (int i = 0; i < 4; ++i)
        #pragma unroll
        for (int r = 0; r < 4; ++r) {
            const float d2 = fmaf(-2.f, acc[i][r], en[r]);
            if (d2 < minv[i]) { minv[i] = d2; mini[i] = code0 + quad * 4 + r; }
        }
}

#define S4_ISSUE(dst, tile)                                              \
    {                                                                    \
        _Pragma("unroll")                                                \
        for (int kc_ = 0; kc_ < 4; ++kc_)                                \
            dst[kc_] = ldT(Ep, (tile) * 4 + kc_, lane);                  \
    }

// ---------------- prep: fragment-pack all weights + E to bf16, E row norms, zero sums.
__global__ __launch_bounds__(256) void vqvae_prep(
    const float* __restrict__ Ef,   const float* __restrict__ We1f,
    const float* __restrict__ We2f, const float* __restrict__ We3f,
    const float* __restrict__ Wd1f, const float* __restrict__ Wd2f,
    const float* __restrict__ Whf,
    u16* __restrict__ Ep,   u16* __restrict__ We1p,
    u16* __restrict__ We2p, u16* __restrict__ We3p,
    u16* __restrict__ Wd1p, u16* __restrict__ Wd2p,
    u16* __restrict__ Whp,  float* __restrict__ ws)
{
    __shared__ float ep[4][16];
    const int b = blockIdx.x, tid = threadIdx.x;
    const int lane = tid & 63, wv = tid >> 6;
    const int lrow = lane & 15, quad = lane >> 4;

    if (b == 0 && tid < 3) {
        if (tid == 2) reinterpret_cast<unsigned*>(ws)[2] = 0u;
        else ws[tid] = 0.f;
    }

    if (b < 98) {
        const float* src; u16* dst; int KT, Tb;
        if      (b < 32) { src = We2f; dst = We2p; KT = 8; Tb = b * 4; }
        else if (b < 48) { src = We3f; dst = We3p; KT = 8; Tb = (b - 32) * 4; }
        else if (b < 64) { src = Wd1f; dst = Wd1p; KT = 4; Tb = (b - 48) * 4; }
        else if (b < 96) { src = Wd2f; dst = Wd2p; KT = 8; Tb = (b - 64) * 4; }
        else             { src = Whf;  dst = Whp;  KT = 8; Tb = (b - 96) * 4; }
        const int T = Tb + wv;
        const int j = T / KT, kc = T % KT;
        const float* p = src + (j * 16 + lrow) * (KT * 32) + kc * 32 + quad * 8;
        const float4 v0 = *reinterpret_cast<const float4*>(p);
        const float4 v1 = *reinterpret_cast<const float4*>(p + 4);
        u16x8 o;
        o[0] = f2b(v0.x); o[1] = f2b(v0.y); o[2] = f2b(v0.z); o[3] = f2b(v0.w);
        o[4] = f2b(v1.x); o[5] = f2b(v1.y); o[6] = f2b(v1.z); o[7] = f2b(v1.w);
        *reinterpret_cast<u16x8*>(dst + (T << 9) + lane * 8) = o;
    } else if (b < 102) {
        // We1 (256x16), K zero-padded to 32: KT=1, tile=j.
        const int T = (b - 98) * 4 + wv;
        u16x8 o = {0, 0, 0, 0, 0, 0, 0, 0};
        if (quad < 2) {
            const float* p = We1f + (T * 16 + lrow) * ADIM + quad * 8;
            const float4 v0 = *reinterpret_cast<const float4*>(p);
            const float4 v1 = *reinterpret_cast<const float4*>(p + 4);
            o[0] = f2b(v0.x); o[1] = f2b(v0.y); o[2] = f2b(v0.z); o[3] = f2b(v0.w);
            o[4] = f2b(v1.x); o[5] = f2b(v1.y); o[6] = f2b(v1.z); o[7] = f2b(v1.w);
        }
        *reinterpret_cast<u16x8*>(We1p + (T << 9) + lane * 8) = o;
    } else {
        // E (2048x128): KT=4; block covers one 16-code group jb, kc = wv. Also |e|^2.
        const int jb = b - 102;
        const int T = jb * 4 + wv;
        const float* p = Ef + (jb * 16 + lrow) * DDIM + wv * 32 + quad * 8;
        const float4 v0 = *reinterpret_cast<const float4*>(p);
        const float4 v1 = *reinterpret_cast<const float4*>(p + 4);
        u16x8 o;
        o[0] = f2b(v0.x); o[1] = f2b(v0.y); o[2] = f2b(v0.z); o[3] = f2b(v0.w);
        o[4] = f2b(v1.x); o[5] = f2b(v1.y); o[6] = f2b(v1.z); o[7] = f2b(v1.w);
        *reinterpret_cast<u16x8*>(Ep + (T << 9) + lane * 8) = o;
        float s = 0.f;
        #pragma unroll
        for (int t = 0; t < 8; ++t) { const float f = b2f(o[t]); s += f * f; }
        s += __shfl_xor(s, 16, 64);
        s += __shfl_xor(s, 32, 64);
        if (lane < 16) ep[wv][lane] = s;
        __syncthreads();
        if (tid < 16) ws[4 + jb * 16 + tid] = ep[0][tid] + ep[1][tid] + ep[2][tid] + ep[3][tid];
    }
}

// ---------------- main fused kernel: 64 rows/block, 8 waves, 2 blocks/CU (16 waves/CU).
// R10 consolidation: R7 champion structure (63.2 us clean) + bias-in-C-init +
// fused argmin-finalize in S5 (9 -> 7 barriers, no qidx round-trip).
// Register games (waves_per_eu, asm keep-alive) all regressed — compiler's ~76-84
// VGPR operating point with remat is FASTER than forced 32-reg hoists (R9/R10).
// Bank conflicts (2.85M) are structural (gemm/epilogue patterns), not S4.
__global__ __launch_bounds__(512) void ActionVQVAE_49452253446164_kernel(
    const float* __restrict__ action,
    const u16* __restrict__ We1p, const float* __restrict__ be1,
    const u16* __restrict__ We2p, const float* __restrict__ be2,
    const u16* __restrict__ We3p, const float* __restrict__ be3,
    const u16* __restrict__ Ep,   const float* __restrict__ enorms,
    const u16* __restrict__ Wd1p, const float* __restrict__ bd1,
    const u16* __restrict__ Wd2p, const float* __restrict__ bd2,
    const u16* __restrict__ Whp,  const float* __restrict__ bh,
    float* __restrict__ sums, unsigned* __restrict__ counter, float* __restrict__ out)
{
    __shared__ u16   bufA[MROWS * SA];   // h1 -> enc(cols 0..127) -> d1
    __shared__ u16   bufB[MROWS * SA];   // h2 -> q(cols 0..127) -> d2
    __shared__ float red_val[8][MROWS];
    __shared__ int   red_idx[8][MROWS];
    __shared__ float wsum[16];

    const int tid  = threadIdx.x;
    const int wave = tid >> 6;           // 0..7
    const int lane = tid & 63;
    const int lrow = lane & 15;
    const int quad = lane >> 4;
    const int kq   = quad * 8;
    const int base = blockIdx.x * MROWS;

    float vq_acc = 0.f, rec_acc = 0.f;
    s16x8 preW[8];   // cross-barrier weight-fragment prefetch staging

    // ---------- S1: h1 = relu(action @ We1^T + be1) -> A   (K=16 zero-padded; NT=2)
    {
        s16x8 w1[2];
        #pragma unroll
        for (int j = 0; j < 2; ++j) w1[j] = ldT(We1p, wave * 2 + j, lane);
        f32x4 acc[4][2];
        acc_init_bias<4, 2>(be1, wave * 32, quad, acc);
        s16x8 b[4];
        s16x8 zf = {0, 0, 0, 0, 0, 0, 0, 0};
        #pragma unroll
        for (int i = 0; i < 4; ++i) b[i] = zf;
        if (quad < 2) {
            #pragma unroll
            for (int i = 0; i < 4; ++i) {
                const float* p = action + (base + i * 16 + lrow) * ADIM + kq;
                const float4 v0 = *reinterpret_cast<const float4*>(p);
                const float4 v1 = *reinterpret_cast<const float4*>(p + 4);
                s16x8 f;
                f[0] = (short)f2b(v0.x); f[1] = (short)f2b(v0.y);
                f[2] = (short)f2b(v0.z); f[3] = (short)f2b(v0.w);
                f[4] = (short)f2b(v1.x); f[5] = (short)f2b(v1.y);
                f[6] = (short)f2b(v1.z); f[7] = (short)f2b(v1.w);
                b[i] = f;
            }
        }
        #pragma unroll
        for (int i = 0; i < 4; ++i)
            #pragma unroll
            for (int j = 0; j < 2; ++j)
                acc[i][j] = __builtin_amdgcn_mfma_f32_16x16x32_bf16(w1[j], b[i], acc[i][j], 0, 0, 0);
        // prefetch S2 first 4 kc-slices (j=2 x kc=4) before the barrier
        #pragma unroll
        for (int j = 0; j < 2; ++j)
            #pragma unroll
            for (int kc = 0; kc < 4; ++kc)
                preW[j * 4 + kc] = ldT(We2p, (wave * 2 + j) * 8 + kc, lane);
        epilogue_st<4, 2>(bufA, wave * 32, lrow, quad, true, acc);
    }
    __syncthreads();

    // ---------- S2: h2 = relu(h1 @ We2^T + be2): A -> B   (NT=2, KC=8, PRE=4)
    {
        f32x4 acc[4][2];
        acc_init_bias<4, 2>(be2, wave * 32, quad, acc);
        gemm_pre<4, 2, 8, 4>(bufA, We2p, 8, wave * 2, preW, lane, lrow, kq, acc);
        // prefetch S3 first 4 kc-slices (NT=1)
        #pragma unroll
        for (int kc = 0; kc < 4; ++kc) preW[kc] = ldT(We3p, wave * 8 + kc, lane);
        epilogue_st<4, 2>(bufB, wave * 32, lrow, quad, true, acc);
    }
    __syncthreads();

    // ---------- S3: enc = h2 @ We3^T + be3: B -> A cols 0..127   (NT=1, KC=8, PRE=4)
    {
        f32x4 acc[4][1];
        acc_init_bias<4, 1>(be3, wave * 16, quad, acc);
        gemm_pre<4, 1, 8, 4>(bufB, We3p, 8, wave, preW, lane, lrow, kq, acc);
        epilogue_st<4, 1>(bufA, wave * 16, lrow, quad, false, acc);
    }
    __syncthreads();

    // ---------- S4: argmin_k |e_k|^2 - 2*enc.e_k; each wave sweeps 256 codes (16 tiles)
    // R7 champion: afr hoist (compiler-managed), E-tiles software-pipelined 2 ahead.
    {
        float minv[4] = {3.4e38f, 3.4e38f, 3.4e38f, 3.4e38f};
        int   mini[4] = {0, 0, 0, 0};
        const int t0 = wave * 16;

        s16x8 pA[4], pB[4];
        S4_ISSUE(pA, t0 + 0);
        S4_ISSUE(pB, t0 + 1);

        s16x8 afr[4][4];
        #pragma unroll
        for (int kc = 0; kc < 4; ++kc)
            #pragma unroll
            for (int i = 0; i < 4; ++i)
                afr[kc][i] = ldb8(bufA + (i * 16 + lrow) * SA + kc * 32 + kq);

        // steady state: consume pX(tile), immediately re-issue 2 ahead into pX
        #pragma unroll 1
        for (int t = 0; t <= 6; ++t) {
            s4_chunk(afr, enorms, pA, (t0 + 2 * t) * 16, quad, minv, mini);
            S4_ISSUE(pA, t0 + 2 * t + 2);
            s4_chunk(afr, enorms, pB, (t0 + 2 * t + 1) * 16, quad, minv, mini);
            S4_ISSUE(pB, t0 + 2 * t + 3);
        }
        // tail: chunks 14,15 (no further issues)
        s4_chunk(afr, enorms, pA, (t0 + 14) * 16, quad, minv, mini);
        s4_chunk(afr, enorms, pB, (t0 + 15) * 16, quad, minv, mini);

        // cross-quad reduce (codes differ only across quads): 2 shfl steps x 4 slices
        #pragma unroll
        for (int off = 16; off < 64; off <<= 1) {
            #pragma unroll
            for (int i = 0; i < 4; ++i) {
                const float ov = __shfl_xor(minv[i], off, 64);
                const int   oi = __shfl_xor(mini[i], off, 64);
                if (ov < minv[i] || (ov == minv[i] && oi < mini[i])) { minv[i] = ov; mini[i] = oi; }
            }
        }
        if (lane < 16) {
            #pragma unroll
            for (int i = 0; i < 4; ++i) {
                red_val[wave][i * 16 + lane] = minv[i];
                red_idx[wave][i * 16 + lane] = mini[i];
            }
        }
        // prefetch S6 first 2 kc-slices (j=2 x kc=2) — independent of the reductions
        #pragma unroll
        for (int j = 0; j < 2; ++j)
            #pragma unroll
            for (int kc = 0; kc < 2; ++kc)
                preW[j * 2 + kc] = ldT(Wd1p, (wave * 2 + j) * 4 + kc, lane);
    }
    __syncthreads();

    // ---------- S5 (fused argmin finalize + gather): each of the 8 threads/row computes
    // the 8-wave min itself (same-address LDS broadcast, conflict-free) -> one barrier
    // and the qidx round-trip removed vs R7.
    {
        const int row  = tid >> 3;             // 64 rows, 8 threads/row
        const int t    = tid & 7;
        const int kc   = t >> 1;
        const int half = t & 1;
        float bv = red_val[0][row]; int bi = red_idx[0][row];
        #pragma unroll
        for (int w = 1; w < 8; ++w) {
            const float v = red_val[w][row]; const int ii = red_idx[w][row];
            if (v < bv || (v == bv && ii < bi)) { bv = v; bi = ii; }
        }
        const int code = bi;
        const int T    = (code >> 4) * 4 + kc;
        const u16* eb  = Ep + (T << 9) + (code & 15) * 8;
        #pragma unroll
        for (int h = 0; h < 2; ++h) {
            const int qd  = half * 2 + h;
            const u16x8 qv = *reinterpret_cast<const u16x8*>(eb + qd * 128);
            const int col = kc * 32 + qd * 8;
            const u16x8 ev = *reinterpret_cast<const u16x8*>(bufA + row * SA + col);
            *reinterpret_cast<u16x8*>(bufB + row * SA + col) = qv;
            #pragma unroll
            for (int e = 0; e < 8; ++e) {
                const float d = b2f(ev[e]) - b2f(qv[e]);
                vq_acc += d * d;
            }
        }
    }
    __syncthreads();

    // ---------- S6: d1 = relu(q @ Wd1^T + bd1): B -> A   (NT=2, KC=4, PRE=2)
    {
        f32x4 acc[4][2];
        acc_init_bias<4, 2>(bd1, wave * 32, quad, acc);
        gemm_pre<4, 2, 4, 2>(bufB, Wd1p, 4, wave * 2, preW, lane, lrow, kq, acc);
        // prefetch S7 first 4 kc-slices (j=2 x kc=4)
        #pragma unroll
        for (int j = 0; j < 2; ++j)
            #pragma unroll
            for (int kc = 0; kc < 4; ++kc)
                preW[j * 4 + kc] = ldT(Wd2p, (wave * 2 + j) * 8 + kc, lane);
        epilogue_st<4, 2>(bufA, wave * 32, lrow, quad, true, acc);
    }
    __syncthreads();

    // ---------- S7: d2 = relu(d1 @ Wd2^T + bd2): A -> B   (NT=2, KC=8, PRE=4)
    {
        f32x4 acc[4][2];
        acc_init_bias<4, 2>(bd2, wave * 32, quad, acc);
        gemm_pre<4, 2, 8, 4>(bufA, Wd2p, 8, wave * 2, preW, lane, lrow, kq, acc);
        // prefetch S8 Wh fragments (waves 0..3 only)
        if (wave < 4) {
            #pragma unroll
            for (int kc = 0; kc < 8; ++kc) preW[kc] = ldT(Whp, kc, lane);
        }
        epilogue_st<4, 2>(bufB, wave * 32, lrow, quad, true, acc);
    }
    __syncthreads();

    // ---------- S8: recons = tanh(d2 @ Wh^T + bh); rec += (recons - action)^2 (fp32)
    if (wave < 4) {
        const int m0 = wave * 16;
        f32x4 acc = *reinterpret_cast<const f32x4*>(bh + quad * 4);   // bias-in-C-init
        #pragma unroll
        for (int kc = 0; kc < 8; ++kc) {
            s16x8 b = ldb8(bufB + (m0 + lrow) * SA + kc * 32 + kq);
            acc = __builtin_amdgcn_mfma_f32_16x16x32_bf16(preW[kc], b, acc, 0, 0, 0);
        }
        const f32x4 av4 = *reinterpret_cast<const f32x4*>(action + (base + m0 + lrow) * ADIM + quad * 4);
        #pragma unroll
        for (int r = 0; r < 4; ++r) {
            const float v = tanhf(acc[r]);
            const float d = v - av4[r];
            rec_acc += d * d;
        }
    }

    // ---------- block reduction + atomics + last-block finalize
    #pragma unroll
    for (int off = 1; off < 64; off <<= 1) {
        vq_acc  += __shfl_xor(vq_acc,  off, 64);
        rec_acc += __shfl_xor(rec_acc, off, 64);
    }
    if (lane == 0) { wsum[wave] = rec_acc; wsum[8 + wave] = vq_acc; }
    __syncthreads();
    if (tid == 0) {
        float r = 0.f, v = 0.f;
        #pragma unroll
        for (int w = 0; w < 8; ++w) { r += wsum[w]; v += wsum[8 + w]; }
        atomicAdd(&sums[0], r);
        atomicAdd(&sums[1], v);
        __threadfence();
        const unsigned old = atomicAdd(counter, 1u);
        if (old == gridDim.x - 1) {
            const float s0 = atomicAdd(&sums[0], 0.f);
            const float s1 = atomicAdd(&sums[1], 0.f);
            const float recons_loss = s0 / (float)(BATCH * ADIM);
            const float vq_loss     = 1.25f * (s1 / (float)(BATCH * DDIM));
            out[0] = recons_loss + vq_loss;
        }
    }
}

extern "C" void kernel_launch(void* const* d_in, const int* in_sizes, int n_in,
                              void* d_out, int out_size, void* d_ws, size_t ws_size,
                              hipStream_t stream)
{
    const float* action = (const float*)d_in[0];
    const float* We1f = (const float*)d_in[1];
    const float* be1  = (const float*)d_in[2];
    const float* We2f = (const float*)d_in[3];
    const float* be2  = (const float*)d_in[4];
    const float* We3f = (const float*)d_in[5];
    const float* be3  = (const float*)d_in[6];
    const float* Ef   = (const float*)d_in[7];
    const float* Wd1f = (const float*)d_in[8];
    const float* bd1  = (const float*)d_in[9];
    const float* Wd2f = (const float*)d_in[10];
    const float* bd2  = (const float*)d_in[11];
    const float* Whf  = (const float*)d_in[12];
    const float* bh   = (const float*)d_in[13];

    float* ws = (float*)d_ws;          // [0]rec [1]vq [2]counter [3]pad [4..2052)enorms
    u16* wb = (u16*)(ws + 2052);       // packed bf16 area, 16B-aligned
    u16* Ep   = wb;                    // 262144
    u16* We1p = Ep   + KCODES * DDIM;  // 8192 (K padded to 32)
    u16* We2p = We1p + HDIM * 32;      // 65536
    u16* We3p = We2p + HDIM * HDIM;    // 32768
    u16* Wd1p = We3p + DDIM * HDIM;    // 32768
    u16* Wd2p = Wd1p + HDIM * DDIM;    // 65536
    u16* Whp  = Wd2p + HDIM * HDIM;    // 4096

    vqvae_prep<<<230, 256, 0, stream>>>(Ef, We1f, We2f, We3f, Wd1f, Wd2f, Whf,
                                        Ep, We1p, We2p, We3p, Wd1p, Wd2p, Whp, ws);
    ActionVQVAE_49452253446164_kernel<<<BATCH / MROWS, 512, 0, stream>>>(
        action, We1p, be1, We2p, be2, We3p, be3,
        Ep, ws + 4, Wd1p, bd1, Wd2p, bd2, Whp, bh,
        ws, (unsigned*)(ws + 2), (float*)d_out);
}